// Round 8
// baseline (609.283 us; speedup 1.0000x reference)
//
#include <hip/hip_runtime.h>
#include <hip/hip_bf16.h>

// Sizes (fixed by the problem)
#define NATOMS 131072
#define NBLK   8192
#define HDIM   256
#define NHEAD  8
#define TDIM   336   // 320 aug dims + 1 (ck_b . Q) + pad

typedef __attribute__((ext_vector_type(8))) short short8;
typedef __attribute__((ext_vector_type(4))) float floatx4;
typedef __attribute__((ext_vector_type(16))) float floatx16;

__device__ __forceinline__ float bfu2f(unsigned short u) {
  unsigned int v = ((unsigned int)u) << 16;
  return __builtin_bit_cast(float, v);
}
__device__ __forceinline__ unsigned short f2bfu(float f) {
  unsigned int u = __builtin_bit_cast(unsigned int, f);
  u += 0x7fffu + ((u >> 16) & 1u);
  return (unsigned short)(u >> 16);
}
// packs bf16(a) into low 16, bf16(b) into high 16 (RNE)
__device__ __forceinline__ unsigned int cvt2(float a, float b) {
  unsigned int r;
  asm("v_cvt_pk_bf16_f32 %0, %1, %2" : "=v"(r) : "v"(a), "v"(b));
  return r;
}

// ---------------- K0: q = seed@Wq+bq ; A_bfT[h][c] = bf16(scale * Wk[c, h*32+d].q[h*32+d]) ; sb[h]
__global__ __launch_bounds__(256) void k0_prep(const float* __restrict__ seed,
    const float* __restrict__ Wq, const float* __restrict__ bq,
    const float* __restrict__ Wk, const float* __restrict__ bk,
    unsigned short* __restrict__ A_bfT, float* __restrict__ sb) {
  __shared__ float qls[256];
  int t = threadIdx.x, b = blockIdx.x;
  float acc = bq[t];
  for (int c = 0; c < 256; ++c) acc += seed[c] * Wq[c * 256 + t];
  qls[t] = acc;
  __syncthreads();
  const float scale = 0.17677669529663687f;  // 1/sqrt(32)
  if (b < 8) {
    int o = b * 256 + t;
    int c = o >> 3, h = o & 7;
    float a = 0.f;
    for (int d = 0; d < 32; ++d) a += Wk[c * 256 + h * 32 + d] * qls[h * 32 + d];
    A_bfT[h * 256 + c] = f2bfu(a * scale);
  } else {
    if (t < 8) {
      float a = 0.f;
      for (int d = 0; d < 32; ++d) a += bk[t * 32 + d] * qls[t * 32 + d];
      sb[t] = a * scale;
    }
    for (int idx = t; idx < 2048; idx += 256) A_bfT[2048 + idx] = 0;  // rows 8..15 = 0
  }
}

// ---------------- Kp1: M[i][c] = cq_w[i,:] . ckT[:,c]  (ckT[j][c]=ck_w[c][j], col 320 = ck_b)
__global__ __launch_bounds__(352) void kp1(const float* __restrict__ cq_w,
    const float* __restrict__ cq_b, const float* __restrict__ ck_w,
    const float* __restrict__ ck_b, float* __restrict__ M, float* __restrict__ vbias) {
  __shared__ float row[256];
  int i = blockIdx.x, t = threadIdx.x;
  if (t < 256) row[t] = cq_w[i * 256 + t];
  __syncthreads();
  if (t < TDIM) {
    float a = 0.f;
    if (t < 320) { const float* w = ck_w + t * 256; for (int j = 0; j < 256; ++j) a += row[j] * w[j]; }
    else if (t == 320) { for (int j = 0; j < 256; ++j) a += row[j] * ck_b[j]; }
    M[i * TDIM + t] = a;
  }
  if (i == 0) {
    __syncthreads();
    if (t < 256) row[t] = cq_b[t];
    __syncthreads();
    if (t < TDIM) {
      float a = 0.f;
      if (t < 320) { const float* w = ck_w + t * 256; for (int j = 0; j < 256; ++j) a += row[j] * w[j]; }
      else if (t == 320) { for (int j = 0; j < 256; ++j) a += row[j] * ck_b[j]; }
      vbias[t] = a;
    }
  }
}

// ---------------- Kp2: MM[p][c] = Wo[p,:] . M[:,c] ; block 256: vb2[c] = bo.M[:,c] + vbias[c]
__global__ __launch_bounds__(352) void kp2(const float* __restrict__ Wo,
    const float* __restrict__ bo, const float* __restrict__ M,
    const float* __restrict__ vbias, float* __restrict__ MM, float* __restrict__ vb2) {
  __shared__ float row[256];
  int p = blockIdx.x, t = threadIdx.x;
  const float* src = (p < 256) ? (Wo + p * 256) : bo;
  if (t < 256) row[t] = src[t];
  __syncthreads();
  if (t < TDIM) {
    float a = 0.f;
    for (int i = 0; i < 256; ++i) a += row[i] * M[i * TDIM + t];
    if (p < 256) MM[p * TDIM + t] = a;
    else vb2[t] = a + vbias[t];
  }
}

// ---------------- Kp3: CV1[k][j] = cv_w[k,:] . cmlp_w1[:,j] ; block 320: cb1 = cv_b@w1m + b1m
__global__ __launch_bounds__(256) void kp3(const float* __restrict__ cv_w,
    const float* __restrict__ cv_b, const float* __restrict__ w1m,
    const float* __restrict__ b1m, float* __restrict__ CV1, float* __restrict__ cb1) {
  __shared__ float row[256];
  int k = blockIdx.x, t = threadIdx.x;
  const float* src = (k < 320) ? (cv_w + k * 256) : cv_b;
  row[t] = src[t];
  __syncthreads();
  float a = 0.f;
  for (int i = 0; i < 256; ++i) a += row[i] * w1m[i * 256 + t];
  if (k < 320) CV1[k * 256 + t] = a;
  else cb1[t] = a + b1m[t];
}

// ---------------- Kcast: W1t, W2t transposed bf16 weights + geomT[q][r] bf16 (r padded to 32)
__global__ __launch_bounds__(256) void kcast(const float* __restrict__ fw1,
    const float* __restrict__ fw2, const float* __restrict__ geom_w,
    unsigned short* __restrict__ W1t, unsigned short* __restrict__ W2t,
    unsigned short* __restrict__ geomT) {
  int b = blockIdx.x, t = threadIdx.x;
  if (b < 512) {
    W1t[b * 256 + t] = f2bfu(fw1[t * 512 + b]);
  } else if (b < 768) {
    int n = b - 512;
    for (int m = 0; m < 2; ++m) {
      int k = t + 256 * m;
      W2t[n * 512 + k] = f2bfu(fw2[k * 256 + n]);
    }
  } else {
    for (int idx = t; idx < 2048; idx += 256) {
      int q = idx >> 5, r = idx & 31;
      geomT[idx] = (r < 16) ? f2bfu(geom_w[r * 64 + q]) : (unsigned short)0;
    }
  }
}

// ---------------- KG1 (MFMA): PMA scores + softmax + pooled y  (4 blocks / wg, 4 waves)
__global__ __launch_bounds__(256) void kg1(const float* __restrict__ x,
    const unsigned short* __restrict__ A_bfT, const float* __restrict__ sb,
    float* __restrict__ y_f) {
  __shared__ unsigned short xs[64][264];
  __shared__ unsigned short wsm[64][8];
  int t = threadIdx.x, wg = blockIdx.x;
  long a0 = (long)wg * 64;
  int B0 = wg * 4;
  int lane = t & 63, w = t >> 6;
  int lrow = lane & 15, hi = lane >> 4, lk = hi * 8;

  const float4* x4 = (const float4*)(x + a0 * 256);
  for (int m = 0; m < 16; ++m) {
    int f4 = t + 256 * m;
    int row = f4 >> 6, c4 = f4 & 63;
    float4 v = x4[f4];
    uint2 q;
    q.x = cvt2(v.x, v.y);
    q.y = cvt2(v.z, v.w);
    *(uint2*)&xs[row][c4 * 4] = q;
  }
  float sblv = (lrow < 8) ? sb[lrow] : 0.f;
  __syncthreads();

  // --- Phase S: scores for atile w.  D row=atom(16w+hi*4+i), col=h(lrow)
  floatx4 zero = {0.f, 0.f, 0.f, 0.f};
  floatx4 accs = zero;
#pragma unroll
  for (int k0 = 0; k0 < 8; ++k0) {
    short8 af = *(const short8*)&xs[16 * w + lrow][k0 * 32 + lk];
    short8 bf = *(const short8*)(A_bfT + lrow * 256 + k0 * 32 + lk);
    accs = __builtin_amdgcn_mfma_f32_16x16x32_bf16(af, bf, accs, 0, 0, 0);
  }
  float sv[4], e[4];
  float mx = -1e30f;
#pragma unroll
  for (int i = 0; i < 4; ++i) { sv[i] = accs[i] + sblv; mx = fmaxf(mx, sv[i]); }
  mx = fmaxf(mx, __shfl_xor(mx, 16));
  mx = fmaxf(mx, __shfl_xor(mx, 32));
  float se = 0.f;
#pragma unroll
  for (int i = 0; i < 4; ++i) { e[i] = __expf(sv[i] - mx); se += e[i]; }
  se += __shfl_xor(se, 16);
  se += __shfl_xor(se, 32);
  float inv = 1.f / fmaxf(se, 1e-20f);
  if (lrow < 8) {
#pragma unroll
    for (int i = 0; i < 4; ++i) wsm[16 * w + hi * 4 + i][lrow] = f2bfu(e[i] * inv);
  }
  __syncthreads();

  // --- Phase Y: y[b][h][c] = sum_i w[i][h]*xs[i][c] via zero-masked K=32 MFMAs.
  int h = lrow & 7, bsel = lrow >> 3;
  short8 A1, A2;
#pragma unroll
  for (int j = 0; j < 8; ++j) {
    int atom = 8 * hi + j;               // 0..31
    unsigned short w1v = wsm[atom][h];        // block atom>>4 (0 or 1)
    unsigned short w2v = wsm[32 + atom][h];   // block 2 or 3
    A1[j] = (bsel == (atom >> 4)) ? (short)w1v : (short)0;
    A2[j] = (bsel == (atom >> 4)) ? (short)w2v : (short)0;
  }
#pragma unroll
  for (int q = 0; q < 4; ++q) {
    int ct = 4 * w + q;
    int cb = ct * 16 + lrow;
    short8 B1, B2;
#pragma unroll
    for (int j = 0; j < 8; ++j) {
      B1[j] = (short)xs[8 * hi + j][cb];
      B2[j] = (short)xs[32 + 8 * hi + j][cb];
    }
    floatx4 d1 = __builtin_amdgcn_mfma_f32_16x16x32_bf16(A1, B1, zero, 0, 0, 0);
    floatx4 d2 = __builtin_amdgcn_mfma_f32_16x16x32_bf16(A2, B2, zero, 0, 0, 0);
#pragma unroll
    for (int i = 0; i < 4; ++i) {
      int r = hi * 4 + i;
      int hh = r & 7, bb = r >> 3;
      y_f[((long)(B0 + bb) * 8 + hh) * 256 + ct * 16 + lrow] = d1[i];
      y_f[((long)(B0 + 2 + bb) * 8 + hh) * 256 + ct * 16 + lrow] = d2[i];
    }
  }
}

// ---------------- GMID: fused g2k+gb1. BP (LDS only) = y@Wv+bv ; T = BP@MM+vb2  (4 blocks / wg)
__global__ __launch_bounds__(256, 4) void gmid(const float* __restrict__ y_f,
    const float* __restrict__ Wv, const float* __restrict__ bv,
    const float* __restrict__ MM, const float* __restrict__ vb2,
    float* __restrict__ T) {
  __shared__ float ys[4][8][260];
  __shared__ float bp[4][260];
  int t = threadIdx.x;
  int B0 = blockIdx.x * 4;
  int h = t >> 5;
#pragma unroll
  for (int m = 0; m < 32; ++m) {
    int flat = t + 256 * m;
    int bb = flat >> 11, rem = flat & 2047;
    ys[bb][rem >> 8][rem & 255] = y_f[((long)(B0 + bb) * 8 + (rem >> 8)) * 256 + (rem & 255)];
  }
  __syncthreads();
  // --- BP phase (each thread owns column j=t; head h = t>>5)
  {
    float acc[4];
    float bvj = bv[t];
#pragma unroll
    for (int bb = 0; bb < 4; ++bb) acc[bb] = bvj;
    const float* wp = Wv + t;
    for (int c = 0; c < 256; c += 4) {
      float w0 = wp[(c + 0) * 256];
      float w1 = wp[(c + 1) * 256];
      float w2 = wp[(c + 2) * 256];
      float w3 = wp[(c + 3) * 256];
#pragma unroll
      for (int bb = 0; bb < 4; ++bb) {
        float4 y4 = *(const float4*)&ys[bb][h][c];
        acc[bb] += w0 * y4.x + w1 * y4.y + w2 * y4.z + w3 * y4.w;
      }
    }
#pragma unroll
    for (int bb = 0; bb < 4; ++bb) bp[bb][t] = acc[bb];
  }
  __syncthreads();
  // --- T phase: T[b][c] = bp[b,:] . MM[:,c] + vb2[c]
#pragma unroll
  for (int chunk = 0; chunk < 2; ++chunk) {
    int c = chunk * 256 + t;
    if (c < TDIM) {
      float vb = vb2[c];
      float acc[4];
#pragma unroll
      for (int bb = 0; bb < 4; ++bb) acc[bb] = vb;
      const float* mc = MM + c;
      for (int j = 0; j < 256; j += 4) {
        float w0 = mc[(j + 0) * TDIM];
        float w1 = mc[(j + 1) * TDIM];
        float w2 = mc[(j + 2) * TDIM];
        float w3 = mc[(j + 3) * TDIM];
#pragma unroll
        for (int bb = 0; bb < 4; ++bb) {
          float4 r4 = *(const float4*)&bp[bb][j];
          acc[bb] += w0 * r4.x + w1 * r4.y + w2 * r4.z + w3 * r4.w;
        }
      }
#pragma unroll
      for (int bb = 0; bb < 4; ++bb)
        T[(long)(B0 + bb) * TDIM + c] = acc[bb];
    }
  }
}

// ---------------- KG3 v2 (MFMA): geometry + cross-attn scores + softmax + z (4 blocks / wg)
__global__ __launch_bounds__(256) void kg3(const float* __restrict__ x,
    const float* __restrict__ pos, const float* __restrict__ T,
    const float* __restrict__ centers, const float* __restrict__ widths,
    const unsigned short* __restrict__ geomT, const float* __restrict__ geom_b,
    float* __restrict__ z_f) {
  __shared__ unsigned short xs[64][264];
  __shared__ unsigned short rbflb[64][32];   // bf16 rbf (k padded to 32)
  __shared__ unsigned short rbfpb[64][72];   // bf16 rbfp (for score MFMA)
  __shared__ float rbfp[64][65];             // f32 rbfp (for z)
  __shared__ unsigned short TbfT[16][328];   // rows 0..3 = T rows of this wg (bf16)
  __shared__ float Tbias[4];
  __shared__ float ps[64][3];
  __shared__ float cent[4][3];
  __shared__ float ctr[16], wid[16];
  __shared__ float w2l[64];
  int t = threadIdx.x, wg = blockIdx.x;
  long a0 = (long)wg * 64;
  int b0 = wg * 4;
  int lane = t & 63, w = t >> 6;
  int lrow = lane & 15, hi = lane >> 4, lk = hi * 8;

  const float4* x4 = (const float4*)(x + a0 * 256);
  for (int m = 0; m < 16; ++m) {
    int f4 = t + 256 * m;
    int row = f4 >> 6, c4 = f4 & 63;
    float4 v = x4[f4];
    uint2 q;
    q.x = cvt2(v.x, v.y);
    q.y = cvt2(v.z, v.w);
    *(uint2*)&xs[row][c4 * 4] = q;
  }
  if (t < 192) ps[t / 3][t % 3] = pos[a0 * 3 + t];
  if (t >= 224 && t < 240) ctr[t - 224] = centers[t - 224];
  if (t >= 240) wid[t - 240] = widths[t - 240];
#pragma unroll
  for (int j = 0; j < 4; ++j)
    for (int c = t; c < 321; c += 256) {
      float v = T[(long)(b0 + j) * TDIM + c];
      if (c < 320) TbfT[j][c] = f2bfu(v);
      else Tbias[j] = v;
    }
  __syncthreads();
  if (t < 12) {
    int b = t / 3, d = t % 3;
    float s = 0.f;
    for (int i = 0; i < 16; ++i) s += ps[b * 16 + i][d];
    cent[b][d] = s * 0.0625f;
  }
  __syncthreads();
  if (t < 64) {
    int b = t >> 4;
    float dx = ps[t][0] - cent[b][0];
    float dy = ps[t][1] - cent[b][1];
    float dz = ps[t][2] - cent[b][2];
    float dist = sqrtf(dx * dx + dy * dy + dz * dz);
    for (int r = 0; r < 16; ++r) {
      float dd = dist - ctr[r];
      rbflb[t][r] = f2bfu(__expf(-dd * dd / (2.f * wid[r] * wid[r])));
      rbflb[t][16 + r] = 0;
    }
  }
  __syncthreads();

  floatx4 zero = {0.f, 0.f, 0.f, 0.f};
  // --- rbfp = rbfl @ geomT^T + geom_b  via MFMA. Wave w owns atom tile w.
  {
    short8 A = *(const short8*)&rbflb[16 * w + lrow][lk];
#pragma unroll
    for (int qt = 0; qt < 4; ++qt) {
      short8 B = *(const short8*)(geomT + (qt * 16 + lrow) * 32 + lk);
      floatx4 d = __builtin_amdgcn_mfma_f32_16x16x32_bf16(A, B, zero, 0, 0, 0);
      float gb = geom_b[qt * 16 + lrow];
#pragma unroll
      for (int i = 0; i < 4; ++i) {
        int atom = 16 * w + hi * 4 + i;
        float v = d[i] + gb;
        rbfp[atom][qt * 16 + lrow] = v;
        rbfpb[atom][qt * 16 + lrow] = f2bfu(v);
      }
    }
  }
  __syncthreads();

  // --- scores: D[atom][j] = Xaug[atom,:] . T[j,:]  (only col j==w valid/used)
  {
    floatx4 acc = zero;
#pragma unroll
    for (int k0 = 0; k0 < 8; ++k0) {
      short8 af = *(const short8*)&xs[16 * w + lrow][k0 * 32 + lk];
      short8 bf = *(const short8*)&TbfT[lrow][k0 * 32 + lk];
      acc = __builtin_amdgcn_mfma_f32_16x16x32_bf16(af, bf, acc, 0, 0, 0);
    }
#pragma unroll
    for (int kq = 0; kq < 2; ++kq) {
      short8 af = *(const short8*)&rbfpb[16 * w + lrow][kq * 32 + lk];
      short8 bf = *(const short8*)&TbfT[lrow][256 + kq * 32 + lk];
      acc = __builtin_amdgcn_mfma_f32_16x16x32_bf16(af, bf, acc, 0, 0, 0);
    }
    float tb = Tbias[w];
    float sv[4], e[4];
    float mx = -1e30f;
#pragma unroll
    for (int i = 0; i < 4; ++i) { sv[i] = (acc[i] + tb) * 0.0625f; mx = fmaxf(mx, sv[i]); }
    mx = fmaxf(mx, __shfl_xor(mx, 16));
    mx = fmaxf(mx, __shfl_xor(mx, 32));
    float se = 0.f;
#pragma unroll
    for (int i = 0; i < 4; ++i) { e[i] = __expf(sv[i] - mx); se += e[i]; }
    se += __shfl_xor(se, 16);
    se += __shfl_xor(se, 32);
    float inv = 1.f / fmaxf(se, 1e-20f);
    if (lrow == w) {
#pragma unroll
      for (int i = 0; i < 4; ++i) w2l[16 * w + hi * 4 + i] = e[i] * inv;
    }
  }
  __syncthreads();

  // --- z: weighted pooling (f32)
  for (int b = 0; b < 4; ++b) {
    float zv = 0.f;
    for (int i = 0; i < 16; ++i) zv += w2l[b * 16 + i] * bfu2f(xs[b * 16 + i][t]);
    z_f[(long)(b0 + b) * 320 + t] = zv;
  }
  {
    int q = t & 63, b = t >> 6;
    float zq = 0.f;
    for (int i = 0; i < 16; ++i) zq += w2l[b * 16 + i] * rbfp[b * 16 + i][q];
    z_f[(long)(b0 + b) * 320 + 256 + q] = zq;
  }
}

// ---------------- Gb2: upd = relu(z@CV1+cb1)@cmlp_w2 + cmlp_b2   (8 blocks / wg)
__global__ __launch_bounds__(256, 4) void gb2(const float* __restrict__ z_f,
    const float* __restrict__ CV1, const float* __restrict__ cb1,
    const float* __restrict__ W2m, const float* __restrict__ b2m,
    float* __restrict__ upd) {
  __shared__ float zrb[8][324];
  __shared__ float prb[8][260];
  int t = threadIdx.x;
  int B0 = blockIdx.x * 8;
  for (int idx = t; idx < 8 * 320; idx += 256) {
    int r = idx / 320, c = idx - r * 320;
    zrb[r][c] = z_f[(long)(B0 + r) * 320 + c];
  }
  __syncthreads();
  {
    float cb = cb1[t];
    float acc[8];
#pragma unroll
    for (int bb = 0; bb < 8; ++bb) acc[bb] = cb;
    const float* wp = CV1 + t;
    for (int k = 0; k < 320; k += 4) {
      float w0 = wp[(k + 0) * 256];
      float w1 = wp[(k + 1) * 256];
      float w2 = wp[(k + 2) * 256];
      float w3 = wp[(k + 3) * 256];
#pragma unroll
      for (int bb = 0; bb < 8; ++bb) {
        float4 z4 = *(const float4*)&zrb[bb][k];
        acc[bb] += w0 * z4.x + w1 * z4.y + w2 * z4.z + w3 * z4.w;
      }
    }
#pragma unroll
    for (int bb = 0; bb < 8; ++bb) prb[bb][t] = fmaxf(acc[bb], 0.f);
  }
  __syncthreads();
  {
    float b2 = b2m[t];
    float acc[8];
#pragma unroll
    for (int bb = 0; bb < 8; ++bb) acc[bb] = b2;
    const float* wp = W2m + t;
    for (int k = 0; k < 256; k += 4) {
      float w0 = wp[(k + 0) * 256];
      float w1 = wp[(k + 1) * 256];
      float w2 = wp[(k + 2) * 256];
      float w3 = wp[(k + 3) * 256];
#pragma unroll
      for (int bb = 0; bb < 8; ++bb) {
        float4 p4 = *(const float4*)&prb[bb][k];
        acc[bb] += w0 * p4.x + w1 * p4.y + w2 * p4.z + w3 * p4.w;
      }
    }
#pragma unroll
    for (int bb = 0; bb < 8; ++bb)
      upd[(long)(B0 + bb) * 256 + t] = acc[bb];
  }
}

// ---------------- KF v7: LN1 + FFN (bf16 MFMA 32x32x16, XOR-swizzled LDS) + residual + LN2
// 64 atoms / wg, 8 waves. GEMM1: wave = 32 hid (ht=w&3) x 32 atoms (at=w>>2) per phase.
// GEMM2: wave = 2x32 out cols x 32 atoms. LDS ops per FLOP halved vs 16x16x32.
// x1s [64][256] / hs [64][128] with 16B-unit swizzle: unit ^= (row & 15).
__global__ __launch_bounds__(512, 4) void kf(const float* __restrict__ x,
    const float* __restrict__ upd, const unsigned short* __restrict__ W1t,
    const unsigned short* __restrict__ W2t, const float* __restrict__ b1,
    const float* __restrict__ b2, const float* __restrict__ g1,
    const float* __restrict__ be1, const float* __restrict__ g2,
    const float* __restrict__ be2, float* __restrict__ out) {
  __shared__ unsigned short x1s[64][256];  // post-LN1 (bf16), swizzled
  __shared__ unsigned short hs[64][128];   // 128-wide hidden slice (bf16), swizzled
  int t = threadIdx.x, wg = blockIdx.x;
  long a0 = (long)wg * 64;
  int b0 = wg * 4;
  int lane = t & 63, w = t >> 6;           // w in 0..7
  int l32 = lane & 31, hi2 = lane >> 5;    // hi2 in 0..1

  // ---- LN1: wave w handles rows w*8 .. w*8+7 (swizzled b64 stores)
  {
    float4 gv1 = ((const float4*)g1)[lane];
    float4 bv1 = ((const float4*)be1)[lane];
#pragma unroll
    for (int rr = 0; rr < 8; ++rr) {
      int row = w * 8 + rr;
      float4 xv = ((const float4*)(x + (a0 + row) * 256))[lane];
      float4 uv = ((const float4*)(upd + (long)(b0 + (row >> 4)) * 256))[lane];
      float4 v;
      v.x = xv.x + uv.x; v.y = xv.y + uv.y; v.z = xv.z + uv.z; v.w = xv.w + uv.w;
      float s = v.x + v.y + v.z + v.w;
      float sq = v.x * v.x + v.y * v.y + v.z * v.z + v.w * v.w;
#pragma unroll
      for (int d = 1; d < 64; d <<= 1) { s += __shfl_xor(s, d); sq += __shfl_xor(sq, d); }
      float mu = s * (1.f / 256.f);
      float var = sq * (1.f / 256.f) - mu * mu;
      float rstd = rsqrtf(fmaxf(var, 0.f) + 1e-5f);
      uint2 q;
      q.x = cvt2((v.x - mu) * rstd * gv1.x + bv1.x, (v.y - mu) * rstd * gv1.y + bv1.y);
      q.y = cvt2((v.z - mu) * rstd * gv1.z + bv1.z, (v.w - mu) * rstd * gv1.w + bv1.w);
      int pc = ((((lane >> 1) ^ (row & 15)) << 3) | ((lane & 1) << 2));
      *(uint2*)&x1s[row][pc] = q;
    }
  }
  __syncthreads();

  int ht = w & 3, at = w >> 2;
  int arow = at * 32 + l32;       // this wave's atom (MFMA B col / D col)
  int asw = arow & 15;            // swizzle key

  floatx16 acc2[2];
#pragma unroll
  for (int o = 0; o < 2; ++o)
    for (int i = 0; i < 16; ++i) acc2[o][i] = 0.f;

  for (int s = 0; s < 4; ++s) {
    // --- GEMM1: D1[32 hid x 32 atoms], K=256 in two 8-step halves
    floatx16 acc1;
#pragma unroll
    for (int i = 0; i < 16; ++i) acc1[i] = 0.f;
    const unsigned short* w1p = W1t + (s * 128 + ht * 32 + l32) * 256 + hi2 * 8;
#pragma unroll
    for (int half = 0; half < 2; ++half) {
      short8 a1[8];
#pragma unroll
      for (int k0 = 0; k0 < 8; ++k0)
        a1[k0] = *(const short8*)(w1p + (half * 8 + k0) * 16);
#pragma unroll
      for (int k0 = 0; k0 < 8; ++k0) {
        int u = (((half * 8 + k0) * 2 + hi2) ^ asw);
        short8 bx = *(const short8*)&x1s[arow][u * 8];
        acc1 = __builtin_amdgcn_mfma_f32_32x32x16_bf16(a1[k0], bx, acc1, 0, 0, 0);
      }
    }
    if (s) __syncthreads();  // all waves done reading hs (prev phase GEMM2)
    // bias + relu + pack -> hs. lane holds D[hid_local = 8g+4*hi2+i][atom = arow]
#pragma unroll
    for (int g = 0; g < 4; ++g) {
      float4 bb = ((const float4*)b1)[s * 32 + ht * 8 + g * 2 + hi2];
      float r0 = fmaxf(acc1[4 * g + 0] + bb.x, 0.f);
      float r1 = fmaxf(acc1[4 * g + 1] + bb.y, 0.f);
      float r2 = fmaxf(acc1[4 * g + 2] + bb.z, 0.f);
      float r3 = fmaxf(acc1[4 * g + 3] + bb.w, 0.f);
      uint2 q;
      q.x = cvt2(r0, r1);
      q.y = cvt2(r2, r3);
      int u = (ht * 4 + g) ^ asw;
      *(uint2*)&hs[arow][u * 8 + hi2 * 4] = q;
    }
    __syncthreads();
    // --- GEMM2: K-slice = this phase's 128. B-frags shared across the 2 out-tiles.
    short8 bh[8];
#pragma unroll
    for (int k0 = 0; k0 < 8; ++k0) {
      int u = ((k0 * 2 + hi2) ^ asw);
      bh[k0] = *(const short8*)&hs[arow][u * 8];
    }
#pragma unroll
    for (int o = 0; o < 2; ++o) {
      const unsigned short* w2p = W2t + ((w & 3) * 32 + o * 128 + l32) * 512 + s * 128 + hi2 * 8;
      short8 a2[8];
#pragma unroll
      for (int k0 = 0; k0 < 8; ++k0)
        a2[k0] = *(const short8*)(w2p + k0 * 16);
#pragma unroll
      for (int k0 = 0; k0 < 8; ++k0)
        acc2[o] = __builtin_amdgcn_mfma_f32_32x32x16_bf16(a2[k0], bh[k0], acc2[o], 0, 0, 0);
    }
  }

  // epilogue: lane holds D[outcol = (w&3)*32 + o*128 + 8g + 4*hi2 + i][atom = arow]
  // residual (bf16 x1) + bias2, packed b64 RMW into swizzled x1s
#pragma unroll
  for (int o = 0; o < 2; ++o)
    for (int g = 0; g < 4; ++g) {
      int colb = (w & 3) * 32 + o * 128 + g * 8 + hi2 * 4;
      float4 bb = ((const float4*)b2)[colb >> 2];
      int u = ((colb >> 3) ^ asw);
      int pc = u * 8 + hi2 * 4;
      ushort4 old = *(const ushort4*)&x1s[arow][pc];
      float r0 = acc2[o][4 * g + 0] + bb.x + bfu2f(old.x);
      float r1 = acc2[o][4 * g + 1] + bb.y + bfu2f(old.y);
      float r2 = acc2[o][4 * g + 2] + bb.z + bfu2f(old.z);
      float r3 = acc2[o][4 * g + 3] + bb.w + bfu2f(old.w);
      uint2 q;
      q.x = cvt2(r0, r1);
      q.y = cvt2(r2, r3);
      *(uint2*)&x1s[arow][pc] = q;
    }
  __syncthreads();

  // ---- LN2 + coalesced store: wave w handles rows w*8 .. w*8+7 (swizzled reads)
  {
    float4 gv2 = ((const float4*)g2)[lane];
    float4 bv2 = ((const float4*)be2)[lane];
#pragma unroll
    for (int rr = 0; rr < 8; ++rr) {
      int row = w * 8 + rr;
      int pc = ((((lane >> 1) ^ (row & 15)) << 3) | ((lane & 1) << 2));
      ushort4 u = *(const ushort4*)&x1s[row][pc];
      float v0 = bfu2f(u.x), v1 = bfu2f(u.y), v2 = bfu2f(u.z), v3 = bfu2f(u.w);
      float s = v0 + v1 + v2 + v3;
      float sq = v0 * v0 + v1 * v1 + v2 * v2 + v3 * v3;
#pragma unroll
      for (int d = 1; d < 64; d <<= 1) { s += __shfl_xor(s, d); sq += __shfl_xor(sq, d); }
      float mu = s * (1.f / 256.f);
      float var = sq * (1.f / 256.f) - mu * mu;
      float rstd = rsqrtf(fmaxf(var, 0.f) + 1e-5f);
      float4 o;
      o.x = (v0 - mu) * rstd * gv2.x + bv2.x;
      o.y = (v1 - mu) * rstd * gv2.y + bv2.y;
      o.z = (v2 - mu) * rstd * gv2.z + bv2.z;
      o.w = (v3 - mu) * rstd * gv2.w + bv2.w;
      ((float4*)(out + (a0 + row) * 256))[lane] = o;
    }
  }
}

extern "C" void kernel_launch(void* const* d_in, const int* in_sizes, int n_in,
                              void* d_out, int out_size, void* d_ws, size_t ws_size,
                              hipStream_t stream) {
  (void)in_sizes; (void)n_in; (void)out_size; (void)ws_size;
  const float* x    = (const float*)d_in[0];
  const float* pos  = (const float*)d_in[1];
  const float* seed = (const float*)d_in[4];
  const float* Wq   = (const float*)d_in[5];
  const float* bq   = (const float*)d_in[6];
  const float* Wk   = (const float*)d_in[7];
  const float* bk   = (const float*)d_in[8];
  const float* Wv   = (const float*)d_in[9];
  const float* bv   = (const float*)d_in[10];
  const float* Wo   = (const float*)d_in[11];
  const float* bo   = (const float*)d_in[12];
  const float* centers = (const float*)d_in[13];
  const float* widths  = (const float*)d_in[14];
  const float* geom_w  = (const float*)d_in[15];
  const float* geom_b  = (const float*)d_in[16];
  const float* cq_w = (const float*)d_in[17];
  const float* cq_b = (const float*)d_in[18];
  const float* ck_w = (const float*)d_in[19];
  const float* ck_b = (const float*)d_in[20];
  const float* cv_w = (const float*)d_in[21];
  const float* cv_b = (const float*)d_in[22];
  const float* w1m  = (const float*)d_in[23];
  const float* b1m  = (const float*)d_in[24];
  const float* w2m  = (const float*)d_in[25];
  const float* b2m  = (const float*)d_in[26];
  const float* fw1  = (const float*)d_in[27];
  const float* fb1  = (const float*)d_in[28];
  const float* fw2  = (const float*)d_in[29];
  const float* fb2  = (const float*)d_in[30];
  const float* g1   = (const float*)d_in[31];
  const float* be1  = (const float*)d_in[32];
  const float* g2   = (const float*)d_in[33];
  const float* be2  = (const float*)d_in[34];

  float* ws = (float*)d_ws;
  float* sb = ws + 0;                                     // 64
  unsigned short* A_bfT = (unsigned short*)(ws + 64);     // 16*256 bf16 = 2048 floats
  float* M     = ws + 2112;     // 256*336 = 86016
  float* vbias = ws + 88128;    // 352
  float* MM    = ws + 88480;    // 256*336 = 86016
  float* vb2   = ws + 174496;   // 352
  float* CV1   = ws + 174848;   // 320*256 = 81920
  float* cb1   = ws + 256768;   // 256
  unsigned short* W1t = (unsigned short*)(ws + 257024);   // 512*256 bf16
  unsigned short* W2t = (unsigned short*)(ws + 322560);   // 256*512 bf16
  float* updw = ws + 388096;                              // 8192*256 f32 -> ends 2485248
  unsigned short* geomT = (unsigned short*)(ws + 2485248); // 64*32 bf16
  // total ws use: ~10 MB

  // scratch inside d_out (134 MB, fully overwritten by kf at the end):
  float* outp = (float*)d_out;
  float* yf  = outp;               // 8192*8*256 f32 = 16,777,216 floats
  float* T   = outp + 16777216;    // 8192*336 f32   =  2,752,512
  float* zf  = outp + 21626880;    // 8192*320 f32   =  2,621,440  (ends 24,248,320 < 33,554,432)

  k0_prep<<<dim3(9), dim3(256), 0, stream>>>(seed, Wq, bq, Wk, bk, A_bfT, sb);
  kp1<<<dim3(256), dim3(352), 0, stream>>>(cq_w, cq_b, ck_w, ck_b, M, vbias);
  kp2<<<dim3(257), dim3(352), 0, stream>>>(Wo, bo, M, vbias, MM, vb2);
  kp3<<<dim3(321), dim3(256), 0, stream>>>(cv_w, cv_b, w1m, b1m, CV1, cb1);
  kcast<<<dim3(769), dim3(256), 0, stream>>>(fw1, fw2, geom_w, W1t, W2t, geomT);
  kg1<<<dim3(2048), dim3(256), 0, stream>>>(x, A_bfT, sb, yf);
  gmid<<<dim3(2048), dim3(256), 0, stream>>>(yf, Wv, bv, MM, vb2, T);
  kg3<<<dim3(2048), dim3(256), 0, stream>>>(x, pos, T, centers, widths, geomT, geom_b, zf);
  gb2<<<dim3(1024), dim3(256), 0, stream>>>(zf, CV1, cb1, w2m, b2m, updw);
  kf<<<dim3(2048), dim3(512), 0, stream>>>(x, updw, W1t, W2t, fb1, fb2, g1, be1, g2, be2, outp);
}

// Round 9
// 430.295 us; speedup vs baseline: 1.4160x; 1.4160x over previous
//
#include <hip/hip_runtime.h>
#include <hip/hip_bf16.h>

// Sizes (fixed by the problem)
#define NATOMS 131072
#define NBLK   8192
#define HDIM   256
#define NHEAD  8
#define TDIM   336   // 320 aug dims + 1 (ck_b . Q) + pad

typedef __attribute__((ext_vector_type(8))) short short8;
typedef __attribute__((ext_vector_type(4))) float floatx4;

__device__ __forceinline__ float bfu2f(unsigned short u) {
  unsigned int v = ((unsigned int)u) << 16;
  return __builtin_bit_cast(float, v);
}
__device__ __forceinline__ unsigned short f2bfu(float f) {
  unsigned int u = __builtin_bit_cast(unsigned int, f);
  u += 0x7fffu + ((u >> 16) & 1u);
  return (unsigned short)(u >> 16);
}
// packs bf16(a) into low 16, bf16(b) into high 16 (RNE)
__device__ __forceinline__ unsigned int cvt2(float a, float b) {
  unsigned int r;
  asm("v_cvt_pk_bf16_f32 %0, %1, %2" : "=v"(r) : "v"(a), "v"(b));
  return r;
}

// ---------------- K0: q = seed@Wq+bq ; A_bfT[h][c] = bf16(scale * Wk[c, h*32+d].q[h*32+d]) ; sb[h]
__global__ __launch_bounds__(256) void k0_prep(const float* __restrict__ seed,
    const float* __restrict__ Wq, const float* __restrict__ bq,
    const float* __restrict__ Wk, const float* __restrict__ bk,
    unsigned short* __restrict__ A_bfT, float* __restrict__ sb) {
  __shared__ float qls[256];
  int t = threadIdx.x, b = blockIdx.x;
  float acc = bq[t];
  for (int c = 0; c < 256; ++c) acc += seed[c] * Wq[c * 256 + t];
  qls[t] = acc;
  __syncthreads();
  const float scale = 0.17677669529663687f;  // 1/sqrt(32)
  if (b < 8) {
    int o = b * 256 + t;
    int c = o >> 3, h = o & 7;
    float a = 0.f;
    for (int d = 0; d < 32; ++d) a += Wk[c * 256 + h * 32 + d] * qls[h * 32 + d];
    A_bfT[h * 256 + c] = f2bfu(a * scale);
  } else {
    if (t < 8) {
      float a = 0.f;
      for (int d = 0; d < 32; ++d) a += bk[t * 32 + d] * qls[t * 32 + d];
      sb[t] = a * scale;
    }
    for (int idx = t; idx < 2048; idx += 256) A_bfT[2048 + idx] = 0;  // rows 8..15 = 0
  }
}

// ---------------- Kp1: M[i][c] = cq_w[i,:] . ckT[:,c]  (ckT[j][c]=ck_w[c][j], col 320 = ck_b)
__global__ __launch_bounds__(352) void kp1(const float* __restrict__ cq_w,
    const float* __restrict__ cq_b, const float* __restrict__ ck_w,
    const float* __restrict__ ck_b, float* __restrict__ M, float* __restrict__ vbias) {
  __shared__ float row[256];
  int i = blockIdx.x, t = threadIdx.x;
  if (t < 256) row[t] = cq_w[i * 256 + t];
  __syncthreads();
  if (t < TDIM) {
    float a = 0.f;
    if (t < 320) { const float* w = ck_w + t * 256; for (int j = 0; j < 256; ++j) a += row[j] * w[j]; }
    else if (t == 320) { for (int j = 0; j < 256; ++j) a += row[j] * ck_b[j]; }
    M[i * TDIM + t] = a;
  }
  if (i == 0) {
    __syncthreads();
    if (t < 256) row[t] = cq_b[t];
    __syncthreads();
    if (t < TDIM) {
      float a = 0.f;
      if (t < 320) { const float* w = ck_w + t * 256; for (int j = 0; j < 256; ++j) a += row[j] * w[j]; }
      else if (t == 320) { for (int j = 0; j < 256; ++j) a += row[j] * ck_b[j]; }
      vbias[t] = a;
    }
  }
}

// ---------------- Kp2: MM[p][c] = Wo[p,:] . M[:,c] ; block 256: vb2[c] = bo.M[:,c] + vbias[c]
__global__ __launch_bounds__(352) void kp2(const float* __restrict__ Wo,
    const float* __restrict__ bo, const float* __restrict__ M,
    const float* __restrict__ vbias, float* __restrict__ MM, float* __restrict__ vb2) {
  __shared__ float row[256];
  int p = blockIdx.x, t = threadIdx.x;
  const float* src = (p < 256) ? (Wo + p * 256) : bo;
  if (t < 256) row[t] = src[t];
  __syncthreads();
  if (t < TDIM) {
    float a = 0.f;
    for (int i = 0; i < 256; ++i) a += row[i] * M[i * TDIM + t];
    if (p < 256) MM[p * TDIM + t] = a;
    else vb2[t] = a + vbias[t];
  }
}

// ---------------- Kp3: CV1[k][j] = cv_w[k,:] . cmlp_w1[:,j] ; block 320: cb1 = cv_b@w1m + b1m
__global__ __launch_bounds__(256) void kp3(const float* __restrict__ cv_w,
    const float* __restrict__ cv_b, const float* __restrict__ w1m,
    const float* __restrict__ b1m, float* __restrict__ CV1, float* __restrict__ cb1) {
  __shared__ float row[256];
  int k = blockIdx.x, t = threadIdx.x;
  const float* src = (k < 320) ? (cv_w + k * 256) : cv_b;
  row[t] = src[t];
  __syncthreads();
  float a = 0.f;
  for (int i = 0; i < 256; ++i) a += row[i] * w1m[i * 256 + t];
  if (k < 320) CV1[k * 256 + t] = a;
  else cb1[t] = a + b1m[t];
}

// ---------------- Kcast: W1t, W2t transposed bf16 weights + geomT[q][r] bf16 (r padded to 32)
__global__ __launch_bounds__(256) void kcast(const float* __restrict__ fw1,
    const float* __restrict__ fw2, const float* __restrict__ geom_w,
    unsigned short* __restrict__ W1t, unsigned short* __restrict__ W2t,
    unsigned short* __restrict__ geomT) {
  int b = blockIdx.x, t = threadIdx.x;
  if (b < 512) {
    W1t[b * 256 + t] = f2bfu(fw1[t * 512 + b]);
  } else if (b < 768) {
    int n = b - 512;
    for (int m = 0; m < 2; ++m) {
      int k = t + 256 * m;
      W2t[n * 512 + k] = f2bfu(fw2[k * 256 + n]);
    }
  } else {
    for (int idx = t; idx < 2048; idx += 256) {
      int q = idx >> 5, r = idx & 31;
      geomT[idx] = (r < 16) ? f2bfu(geom_w[r * 64 + q]) : (unsigned short)0;
    }
  }
}

// ---------------- KGM: fused kg1 + gmid. PMA scores + softmax + pooled y (regs) ->
// ys in LDS (aliased over xs) -> BP = y@Wv+bv (LDS) -> T = BP@MM+vb2 (global).
// 4 blocks / wg, 4 waves, ~39KB LDS -> 4 wgs/CU.
__global__ __launch_bounds__(256, 4) void kgm(const float* __restrict__ x,
    const unsigned short* __restrict__ A_bfT, const float* __restrict__ sb,
    const float* __restrict__ Wv, const float* __restrict__ bv,
    const float* __restrict__ MM, const float* __restrict__ vb2,
    float* __restrict__ T) {
  __shared__ __align__(16) char buf[33792];            // xs (33792B) aliased with ys (33280B)
  unsigned short (*xs)[264] = (unsigned short(*)[264])buf;
  float (*ys)[8][260] = (float(*)[8][260])buf;
  __shared__ unsigned short wsm[64][8];
  __shared__ float bp[4][260];
  int t = threadIdx.x, wg = blockIdx.x;
  long a0 = (long)wg * 64;
  int B0 = wg * 4;
  int lane = t & 63, w = t >> 6;
  int lrow = lane & 15, hi = lane >> 4, lk = hi * 8;

  const float4* x4 = (const float4*)(x + a0 * 256);
  for (int m = 0; m < 16; ++m) {
    int f4 = t + 256 * m;
    int row = f4 >> 6, c4 = f4 & 63;
    float4 v = x4[f4];
    uint2 q;
    q.x = cvt2(v.x, v.y);
    q.y = cvt2(v.z, v.w);
    *(uint2*)&xs[row][c4 * 4] = q;
  }
  float sblv = (lrow < 8) ? sb[lrow] : 0.f;
  __syncthreads();

  // --- Phase S: scores for atile w.  D row=atom(16w+hi*4+i), col=h(lrow)
  floatx4 zero = {0.f, 0.f, 0.f, 0.f};
  floatx4 accs = zero;
#pragma unroll
  for (int k0 = 0; k0 < 8; ++k0) {
    short8 af = *(const short8*)&xs[16 * w + lrow][k0 * 32 + lk];
    short8 bf = *(const short8*)(A_bfT + lrow * 256 + k0 * 32 + lk);
    accs = __builtin_amdgcn_mfma_f32_16x16x32_bf16(af, bf, accs, 0, 0, 0);
  }
  {
    float sv[4], e[4];
    float mx = -1e30f;
#pragma unroll
    for (int i = 0; i < 4; ++i) { sv[i] = accs[i] + sblv; mx = fmaxf(mx, sv[i]); }
    mx = fmaxf(mx, __shfl_xor(mx, 16));
    mx = fmaxf(mx, __shfl_xor(mx, 32));
    float se = 0.f;
#pragma unroll
    for (int i = 0; i < 4; ++i) { e[i] = __expf(sv[i] - mx); se += e[i]; }
    se += __shfl_xor(se, 16);
    se += __shfl_xor(se, 32);
    float inv = 1.f / fmaxf(se, 1e-20f);
    if (lrow < 8) {
#pragma unroll
      for (int i = 0; i < 4; ++i) wsm[16 * w + hi * 4 + i][lrow] = f2bfu(e[i] * inv);
    }
  }
  __syncthreads();

  // --- Phase Y (into registers): y[b][h][c] = sum_i w[i][h]*xs[i][c], zero-masked K=32 MFMAs
  int h = lrow & 7, bsel = lrow >> 3;
  short8 A1, A2;
#pragma unroll
  for (int j = 0; j < 8; ++j) {
    int atom = 8 * hi + j;               // 0..31
    unsigned short w1v = wsm[atom][h];        // block atom>>4 (0 or 1)
    unsigned short w2v = wsm[32 + atom][h];   // block 2 or 3
    A1[j] = (bsel == (atom >> 4)) ? (short)w1v : (short)0;
    A2[j] = (bsel == (atom >> 4)) ? (short)w2v : (short)0;
  }
  floatx4 d1r[4], d2r[4];
#pragma unroll
  for (int q = 0; q < 4; ++q) {
    int ct = 4 * w + q;
    int cb = ct * 16 + lrow;
    short8 B1, B2;
#pragma unroll
    for (int j = 0; j < 8; ++j) {
      B1[j] = (short)xs[8 * hi + j][cb];
      B2[j] = (short)xs[32 + 8 * hi + j][cb];
    }
    d1r[q] = __builtin_amdgcn_mfma_f32_16x16x32_bf16(A1, B1, zero, 0, 0, 0);
    d2r[q] = __builtin_amdgcn_mfma_f32_16x16x32_bf16(A2, B2, zero, 0, 0, 0);
  }
  __syncthreads();  // all xs reads complete before ys overwrites the buffer

  // --- spill y to LDS (overwrites xs region)
#pragma unroll
  for (int q = 0; q < 4; ++q) {
    int ct = 4 * w + q;
#pragma unroll
    for (int i = 0; i < 4; ++i) {
      int r = hi * 4 + i;
      int hh = r & 7, bb = r >> 3;
      ys[bb][hh][ct * 16 + lrow] = d1r[q][i];
      ys[2 + bb][hh][ct * 16 + lrow] = d2r[q][i];
    }
  }
  __syncthreads();

  // --- BP phase: BP[b][j=t] = y[b][t>>5,:] . Wv[:,t] + bv[t]
  {
    int h2 = t >> 5;
    float acc[4];
    float bvj = bv[t];
#pragma unroll
    for (int bb = 0; bb < 4; ++bb) acc[bb] = bvj;
    const float* wp = Wv + t;
    for (int c = 0; c < 256; c += 4) {
      float w0 = wp[(c + 0) * 256];
      float w1 = wp[(c + 1) * 256];
      float w2 = wp[(c + 2) * 256];
      float w3 = wp[(c + 3) * 256];
#pragma unroll
      for (int bb = 0; bb < 4; ++bb) {
        float4 y4 = *(const float4*)&ys[bb][h2][c];
        acc[bb] += w0 * y4.x + w1 * y4.y + w2 * y4.z + w3 * y4.w;
      }
    }
#pragma unroll
    for (int bb = 0; bb < 4; ++bb) bp[bb][t] = acc[bb];
  }
  __syncthreads();

  // --- T phase: T[b][c] = bp[b,:] . MM[:,c] + vb2[c]
#pragma unroll
  for (int chunk = 0; chunk < 2; ++chunk) {
    int c = chunk * 256 + t;
    if (c < TDIM) {
      float vb = vb2[c];
      float acc[4];
#pragma unroll
      for (int bb = 0; bb < 4; ++bb) acc[bb] = vb;
      const float* mc = MM + c;
      for (int j = 0; j < 256; j += 4) {
        float w0 = mc[(j + 0) * TDIM];
        float w1 = mc[(j + 1) * TDIM];
        float w2 = mc[(j + 2) * TDIM];
        float w3 = mc[(j + 3) * TDIM];
#pragma unroll
        for (int bb = 0; bb < 4; ++bb) {
          float4 r4 = *(const float4*)&bp[bb][j];
          acc[bb] += w0 * r4.x + w1 * r4.y + w2 * r4.z + w3 * r4.w;
        }
      }
#pragma unroll
      for (int bb = 0; bb < 4; ++bb)
        T[(long)(B0 + bb) * TDIM + c] = acc[bb];
    }
  }
}

// ---------------- KG3 v2 (MFMA): geometry + cross-attn scores + softmax + z (4 blocks / wg)
__global__ __launch_bounds__(256) void kg3(const float* __restrict__ x,
    const float* __restrict__ pos, const float* __restrict__ T,
    const float* __restrict__ centers, const float* __restrict__ widths,
    const unsigned short* __restrict__ geomT, const float* __restrict__ geom_b,
    float* __restrict__ z_f) {
  __shared__ unsigned short xs[64][264];
  __shared__ unsigned short rbflb[64][32];   // bf16 rbf (k padded to 32)
  __shared__ unsigned short rbfpb[64][72];   // bf16 rbfp (for score MFMA)
  __shared__ float rbfp[64][65];             // f32 rbfp (for z)
  __shared__ unsigned short TbfT[16][328];   // rows 0..3 = T rows of this wg (bf16)
  __shared__ float Tbias[4];
  __shared__ float ps[64][3];
  __shared__ float cent[4][3];
  __shared__ float ctr[16], wid[16];
  __shared__ float w2l[64];
  int t = threadIdx.x, wg = blockIdx.x;
  long a0 = (long)wg * 64;
  int b0 = wg * 4;
  int lane = t & 63, w = t >> 6;
  int lrow = lane & 15, hi = lane >> 4, lk = hi * 8;

  const float4* x4 = (const float4*)(x + a0 * 256);
  for (int m = 0; m < 16; ++m) {
    int f4 = t + 256 * m;
    int row = f4 >> 6, c4 = f4 & 63;
    float4 v = x4[f4];
    uint2 q;
    q.x = cvt2(v.x, v.y);
    q.y = cvt2(v.z, v.w);
    *(uint2*)&xs[row][c4 * 4] = q;
  }
  if (t < 192) ps[t / 3][t % 3] = pos[a0 * 3 + t];
  if (t >= 224 && t < 240) ctr[t - 224] = centers[t - 224];
  if (t >= 240) wid[t - 240] = widths[t - 240];
#pragma unroll
  for (int j = 0; j < 4; ++j)
    for (int c = t; c < 321; c += 256) {
      float v = T[(long)(b0 + j) * TDIM + c];
      if (c < 320) TbfT[j][c] = f2bfu(v);
      else Tbias[j] = v;
    }
  __syncthreads();
  if (t < 12) {
    int b = t / 3, d = t % 3;
    float s = 0.f;
    for (int i = 0; i < 16; ++i) s += ps[b * 16 + i][d];
    cent[b][d] = s * 0.0625f;
  }
  __syncthreads();
  if (t < 64) {
    int b = t >> 4;
    float dx = ps[t][0] - cent[b][0];
    float dy = ps[t][1] - cent[b][1];
    float dz = ps[t][2] - cent[b][2];
    float dist = sqrtf(dx * dx + dy * dy + dz * dz);
    for (int r = 0; r < 16; ++r) {
      float dd = dist - ctr[r];
      rbflb[t][r] = f2bfu(__expf(-dd * dd / (2.f * wid[r] * wid[r])));
      rbflb[t][16 + r] = 0;
    }
  }
  __syncthreads();

  floatx4 zero = {0.f, 0.f, 0.f, 0.f};
  // --- rbfp = rbfl @ geomT^T + geom_b  via MFMA. Wave w owns atom tile w.
  {
    short8 A = *(const short8*)&rbflb[16 * w + lrow][lk];
#pragma unroll
    for (int qt = 0; qt < 4; ++qt) {
      short8 B = *(const short8*)(geomT + (qt * 16 + lrow) * 32 + lk);
      floatx4 d = __builtin_amdgcn_mfma_f32_16x16x32_bf16(A, B, zero, 0, 0, 0);
      float gb = geom_b[qt * 16 + lrow];
#pragma unroll
      for (int i = 0; i < 4; ++i) {
        int atom = 16 * w + hi * 4 + i;
        float v = d[i] + gb;
        rbfp[atom][qt * 16 + lrow] = v;
        rbfpb[atom][qt * 16 + lrow] = f2bfu(v);
      }
    }
  }
  __syncthreads();

  // --- scores: D[atom][j] = Xaug[atom,:] . T[j,:]  (only col j==w valid/used)
  {
    floatx4 acc = zero;
#pragma unroll
    for (int k0 = 0; k0 < 8; ++k0) {
      short8 af = *(const short8*)&xs[16 * w + lrow][k0 * 32 + lk];
      short8 bf = *(const short8*)&TbfT[lrow][k0 * 32 + lk];
      acc = __builtin_amdgcn_mfma_f32_16x16x32_bf16(af, bf, acc, 0, 0, 0);
    }
#pragma unroll
    for (int kq = 0; kq < 2; ++kq) {
      short8 af = *(const short8*)&rbfpb[16 * w + lrow][kq * 32 + lk];
      short8 bf = *(const short8*)&TbfT[lrow][256 + kq * 32 + lk];
      acc = __builtin_amdgcn_mfma_f32_16x16x32_bf16(af, bf, acc, 0, 0, 0);
    }
    float tb = Tbias[w];
    float sv[4], e[4];
    float mx = -1e30f;
#pragma unroll
    for (int i = 0; i < 4; ++i) { sv[i] = (acc[i] + tb) * 0.0625f; mx = fmaxf(mx, sv[i]); }
    mx = fmaxf(mx, __shfl_xor(mx, 16));
    mx = fmaxf(mx, __shfl_xor(mx, 32));
    float se = 0.f;
#pragma unroll
    for (int i = 0; i < 4; ++i) { e[i] = __expf(sv[i] - mx); se += e[i]; }
    se += __shfl_xor(se, 16);
    se += __shfl_xor(se, 32);
    float inv = 1.f / fmaxf(se, 1e-20f);
    if (lrow == w) {
#pragma unroll
      for (int i = 0; i < 4; ++i) w2l[16 * w + hi * 4 + i] = e[i] * inv;
    }
  }
  __syncthreads();

  // --- z: weighted pooling (f32)
  for (int b = 0; b < 4; ++b) {
    float zv = 0.f;
    for (int i = 0; i < 16; ++i) zv += w2l[b * 16 + i] * bfu2f(xs[b * 16 + i][t]);
    z_f[(long)(b0 + b) * 320 + t] = zv;
  }
  {
    int q = t & 63, b = t >> 6;
    float zq = 0.f;
    for (int i = 0; i < 16; ++i) zq += w2l[b * 16 + i] * rbfp[b * 16 + i][q];
    z_f[(long)(b0 + b) * 320 + 256 + q] = zq;
  }
}

// ---------------- Gb2: upd = relu(z@CV1+cb1)@cmlp_w2 + cmlp_b2   (8 blocks / wg)
__global__ __launch_bounds__(256, 4) void gb2(const float* __restrict__ z_f,
    const float* __restrict__ CV1, const float* __restrict__ cb1,
    const float* __restrict__ W2m, const float* __restrict__ b2m,
    float* __restrict__ upd) {
  __shared__ float zrb[8][324];
  __shared__ float prb[8][260];
  int t = threadIdx.x;
  int B0 = blockIdx.x * 8;
  for (int idx = t; idx < 8 * 320; idx += 256) {
    int r = idx / 320, c = idx - r * 320;
    zrb[r][c] = z_f[(long)(B0 + r) * 320 + c];
  }
  __syncthreads();
  {
    float cb = cb1[t];
    float acc[8];
#pragma unroll
    for (int bb = 0; bb < 8; ++bb) acc[bb] = cb;
    const float* wp = CV1 + t;
    for (int k = 0; k < 320; k += 4) {
      float w0 = wp[(k + 0) * 256];
      float w1 = wp[(k + 1) * 256];
      float w2 = wp[(k + 2) * 256];
      float w3 = wp[(k + 3) * 256];
#pragma unroll
      for (int bb = 0; bb < 8; ++bb) {
        float4 z4 = *(const float4*)&zrb[bb][k];
        acc[bb] += w0 * z4.x + w1 * z4.y + w2 * z4.z + w3 * z4.w;
      }
    }
#pragma unroll
    for (int bb = 0; bb < 8; ++bb) prb[bb][t] = fmaxf(acc[bb], 0.f);
  }
  __syncthreads();
  {
    float b2 = b2m[t];
    float acc[8];
#pragma unroll
    for (int bb = 0; bb < 8; ++bb) acc[bb] = b2;
    const float* wp = W2m + t;
    for (int k = 0; k < 256; k += 4) {
      float w0 = wp[(k + 0) * 256];
      float w1 = wp[(k + 1) * 256];
      float w2 = wp[(k + 2) * 256];
      float w3 = wp[(k + 3) * 256];
#pragma unroll
      for (int bb = 0; bb < 8; ++bb) {
        float4 p4 = *(const float4*)&prb[bb][k];
        acc[bb] += w0 * p4.x + w1 * p4.y + w2 * p4.z + w3 * p4.w;
      }
    }
#pragma unroll
    for (int bb = 0; bb < 8; ++bb)
      upd[(long)(B0 + bb) * 256 + t] = acc[bb];
  }
}

// ---------------- KF v4 (proven): LN1 + FFN (bf16 MFMA) + residual + LN2
// 64 atoms / wg, 8 waves. Wave = 16 hid cols x 64 atoms (no weight duplication),
// swapped MFMA operands (D=[hid][atom] -> packed b64 hs stores, packed epilogue),
// weight frags hoisted into registers. LDS 51.2KB -> 3 blocks/CU.
__global__ __launch_bounds__(512, 4) void kf(const float* __restrict__ x,
    const float* __restrict__ upd, const unsigned short* __restrict__ W1t,
    const unsigned short* __restrict__ W2t, const float* __restrict__ b1,
    const float* __restrict__ b2, const float* __restrict__ g1,
    const float* __restrict__ be1, const float* __restrict__ g2,
    const float* __restrict__ be2, float* __restrict__ out) {
  __shared__ unsigned short x1s[64][264];  // post-LN1 (bf16), stride 528B (132 dw ≡ 4 mod 32)
  __shared__ unsigned short hs[64][136];   // 128-wide hidden slice, stride 272B (68 dw ≡ 4 mod 32)
  int t = threadIdx.x, wg = blockIdx.x;
  long a0 = (long)wg * 64;
  int b0 = wg * 4;
  int lane = t & 63, w = t >> 6;           // w in 0..7
  int lrow = lane & 15, hi = lane >> 4;    // hi in 0..3
  int lk = hi * 8;

  // ---- LN1: wave w handles rows w*8 .. w*8+7
  {
    float4 gv1 = ((const float4*)g1)[lane];
    float4 bv1 = ((const float4*)be1)[lane];
#pragma unroll
    for (int rr = 0; rr < 8; ++rr) {
      int row = w * 8 + rr;
      float4 xv = ((const float4*)(x + (a0 + row) * 256))[lane];
      float4 uv = ((const float4*)(upd + (long)(b0 + (row >> 4)) * 256))[lane];
      float4 v;
      v.x = xv.x + uv.x; v.y = xv.y + uv.y; v.z = xv.z + uv.z; v.w = xv.w + uv.w;
      float s = v.x + v.y + v.z + v.w;
      float sq = v.x * v.x + v.y * v.y + v.z * v.z + v.w * v.w;
#pragma unroll
      for (int d = 1; d < 64; d <<= 1) { s += __shfl_xor(s, d); sq += __shfl_xor(sq, d); }
      float mu = s * (1.f / 256.f);
      float var = sq * (1.f / 256.f) - mu * mu;
      float rstd = rsqrtf(fmaxf(var, 0.f) + 1e-5f);
      uint2 q;
      q.x = cvt2((v.x - mu) * rstd * gv1.x + bv1.x, (v.y - mu) * rstd * gv1.y + bv1.y);
      q.y = cvt2((v.z - mu) * rstd * gv1.z + bv1.z, (v.w - mu) * rstd * gv1.w + bv1.w);
      *(uint2*)&x1s[row][lane * 4] = q;
    }
  }
  __syncthreads();

  floatx4 zero = {0.f, 0.f, 0.f, 0.f};
  floatx4 acc2[2][4];  // [cb][rb]: D[outcol][atom]
#pragma unroll
  for (int cb = 0; cb < 2; ++cb)
    for (int rb = 0; rb < 4; ++rb) acc2[cb][rb] = zero;

  for (int s = 0; s < 4; ++s) {
    // --- hoist GEMM1 weight frags: wave's 16 hidden cols, full K=256
    int hc = s * 128 + w * 16 + lrow;
    short8 wf[8];
#pragma unroll
    for (int k0 = 0; k0 < 8; ++k0)
      wf[k0] = *(const short8*)(W1t + hc * 256 + k0 * 32 + lk);
    // --- GEMM1: A=W1 (m=hid), B=x (n=atom) -> D[hid][atom]
    floatx4 acc1[4] = {zero, zero, zero, zero};
#pragma unroll
    for (int k0 = 0; k0 < 8; ++k0) {
      short8 af0 = *(const short8*)&x1s[0 + lrow][k0 * 32 + lk];
      short8 af1 = *(const short8*)&x1s[16 + lrow][k0 * 32 + lk];
      short8 af2 = *(const short8*)&x1s[32 + lrow][k0 * 32 + lk];
      short8 af3 = *(const short8*)&x1s[48 + lrow][k0 * 32 + lk];
      acc1[0] = __builtin_amdgcn_mfma_f32_16x16x32_bf16(wf[k0], af0, acc1[0], 0, 0, 0);
      acc1[1] = __builtin_amdgcn_mfma_f32_16x16x32_bf16(wf[k0], af1, acc1[1], 0, 0, 0);
      acc1[2] = __builtin_amdgcn_mfma_f32_16x16x32_bf16(wf[k0], af2, acc1[2], 0, 0, 0);
      acc1[3] = __builtin_amdgcn_mfma_f32_16x16x32_bf16(wf[k0], af3, acc1[3], 0, 0, 0);
    }
    // --- hoist GEMM2 weight frags (latency hides under barriers + hs writes)
    short8 wf2[8];
#pragma unroll
    for (int cb = 0; cb < 2; ++cb)
      for (int ks = 0; ks < 4; ++ks)
        wf2[cb * 4 + ks] = *(const short8*)(W2t + (w * 32 + cb * 16 + lrow) * 512 + s * 128 + ks * 32 + lk);
    // bias1 for hid = s*128 + w*16 + hi*4 + i
    float4 b4 = ((const float4*)b1)[s * 32 + w * 4 + hi];
    __syncthreads();  // previous GEMM2 finished reading hs
    // lane holds D[hid = w*16+hi*4+i][atom = rb*16+lrow] -> packed b64 store
#pragma unroll
    for (int rb = 0; rb < 4; ++rb) {
      float r0 = fmaxf(acc1[rb][0] + b4.x, 0.f);
      float r1 = fmaxf(acc1[rb][1] + b4.y, 0.f);
      float r2 = fmaxf(acc1[rb][2] + b4.z, 0.f);
      float r3 = fmaxf(acc1[rb][3] + b4.w, 0.f);
      uint2 q;
      q.x = cvt2(r0, r1);
      q.y = cvt2(r2, r3);
      *(uint2*)&hs[rb * 16 + lrow][w * 16 + hi * 4] = q;
    }
    __syncthreads();
    // --- GEMM2 partial: A=W2 (m=outcol), B=hs (n=atom), K-slice = this phase's 128
#pragma unroll
    for (int ks = 0; ks < 4; ++ks) {
      short8 a20 = *(const short8*)&hs[0 + lrow][ks * 32 + lk];
      short8 a21 = *(const short8*)&hs[16 + lrow][ks * 32 + lk];
      short8 a22 = *(const short8*)&hs[32 + lrow][ks * 32 + lk];
      short8 a23 = *(const short8*)&hs[48 + lrow][ks * 32 + lk];
#pragma unroll
      for (int cb = 0; cb < 2; ++cb) {
        acc2[cb][0] = __builtin_amdgcn_mfma_f32_16x16x32_bf16(wf2[cb * 4 + ks], a20, acc2[cb][0], 0, 0, 0);
        acc2[cb][1] = __builtin_amdgcn_mfma_f32_16x16x32_bf16(wf2[cb * 4 + ks], a21, acc2[cb][1], 0, 0, 0);
        acc2[cb][2] = __builtin_amdgcn_mfma_f32_16x16x32_bf16(wf2[cb * 4 + ks], a22, acc2[cb][2], 0, 0, 0);
        acc2[cb][3] = __builtin_amdgcn_mfma_f32_16x16x32_bf16(wf2[cb * 4 + ks], a23, acc2[cb][3], 0, 0, 0);
      }
    }
  }

  // epilogue: lane holds D[outcol = w*32+cb*16+hi*4+i][atom = rb*16+lrow]
  // residual (bf16 x1) + bias2, packed b64 RMW into x1s
#pragma unroll
  for (int cb = 0; cb < 2; ++cb) {
    float4 b4 = ((const float4*)b2)[w * 8 + cb * 4 + hi];
    int colb = w * 32 + cb * 16 + hi * 4;
#pragma unroll
    for (int rb = 0; rb < 4; ++rb) {
      int atom = rb * 16 + lrow;
      ushort4 old = *(const ushort4*)&x1s[atom][colb];
      float r0 = acc2[cb][rb][0] + b4.x + bfu2f(old.x);
      float r1 = acc2[cb][rb][1] + b4.y + bfu2f(old.y);
      float r2 = acc2[cb][rb][2] + b4.z + bfu2f(old.z);
      float r3 = acc2[cb][rb][3] + b4.w + bfu2f(old.w);
      uint2 q;
      q.x = cvt2(r0, r1);
      q.y = cvt2(r2, r3);
      *(uint2*)&x1s[atom][colb] = q;
    }
  }
  __syncthreads();

  // ---- LN2 + coalesced store: wave w handles rows w*8 .. w*8+7
  {
    float4 gv2 = ((const float4*)g2)[lane];
    float4 bv2 = ((const float4*)be2)[lane];
#pragma unroll
    for (int rr = 0; rr < 8; ++rr) {
      int row = w * 8 + rr;
      ushort4 u = *(const ushort4*)&x1s[row][lane * 4];
      float v0 = bfu2f(u.x), v1 = bfu2f(u.y), v2 = bfu2f(u.z), v3 = bfu2f(u.w);
      float s = v0 + v1 + v2 + v3;
      float sq = v0 * v0 + v1 * v1 + v2 * v2 + v3 * v3;
#pragma unroll
      for (int d = 1; d < 64; d <<= 1) { s += __shfl_xor(s, d); sq += __shfl_xor(sq, d); }
      float mu = s * (1.f / 256.f);
      float var = sq * (1.f / 256.f) - mu * mu;
      float rstd = rsqrtf(fmaxf(var, 0.f) + 1e-5f);
      float4 o;
      o.x = (v0 - mu) * rstd * gv2.x + bv2.x;
      o.y = (v1 - mu) * rstd * gv2.y + bv2.y;
      o.z = (v2 - mu) * rstd * gv2.z + bv2.z;
      o.w = (v3 - mu) * rstd * gv2.w + bv2.w;
      ((float4*)(out + (a0 + row) * 256))[lane] = o;
    }
  }
}

extern "C" void kernel_launch(void* const* d_in, const int* in_sizes, int n_in,
                              void* d_out, int out_size, void* d_ws, size_t ws_size,
                              hipStream_t stream) {
  (void)in_sizes; (void)n_in; (void)out_size; (void)ws_size;
  const float* x    = (const float*)d_in[0];
  const float* pos  = (const float*)d_in[1];
  const float* seed = (const float*)d_in[4];
  const float* Wq   = (const float*)d_in[5];
  const float* bq   = (const float*)d_in[6];
  const float* Wk   = (const float*)d_in[7];
  const float* bk   = (const float*)d_in[8];
  const float* Wv   = (const float*)d_in[9];
  const float* bv   = (const float*)d_in[10];
  const float* Wo   = (const float*)d_in[11];
  const float* bo   = (const float*)d_in[12];
  const float* centers = (const float*)d_in[13];
  const float* widths  = (const float*)d_in[14];
  const float* geom_w  = (const float*)d_in[15];
  const float* geom_b  = (const float*)d_in[16];
  const float* cq_w = (const float*)d_in[17];
  const float* cq_b = (const float*)d_in[18];
  const float* ck_w = (const float*)d_in[19];
  const float* ck_b = (const float*)d_in[20];
  const float* cv_w = (const float*)d_in[21];
  const float* cv_b = (const float*)d_in[22];
  const float* w1m  = (const float*)d_in[23];
  const float* b1m  = (const float*)d_in[24];
  const float* w2m  = (const float*)d_in[25];
  const float* b2m  = (const float*)d_in[26];
  const float* fw1  = (const float*)d_in[27];
  const float* fb1  = (const float*)d_in[28];
  const float* fw2  = (const float*)d_in[29];
  const float* fb2  = (const float*)d_in[30];
  const float* g1   = (const float*)d_in[31];
  const float* be1  = (const float*)d_in[32];
  const float* g2   = (const float*)d_in[33];
  const float* be2  = (const float*)d_in[34];

  float* ws = (float*)d_ws;
  float* sb = ws + 0;                                     // 64
  unsigned short* A_bfT = (unsigned short*)(ws + 64);     // 16*256 bf16 = 2048 floats
  float* M     = ws + 2112;     // 256*336 = 86016
  float* vbias = ws + 88128;    // 352
  float* MM    = ws + 88480;    // 256*336 = 86016
  float* vb2   = ws + 174496;   // 352
  float* CV1   = ws + 174848;   // 320*256 = 81920
  float* cb1   = ws + 256768;   // 256
  unsigned short* W1t = (unsigned short*)(ws + 257024);   // 512*256 bf16
  unsigned short* W2t = (unsigned short*)(ws + 322560);   // 256*512 bf16
  float* updw = ws + 388096;                              // 8192*256 f32 -> ends 2485248
  unsigned short* geomT = (unsigned short*)(ws + 2485248); // 64*32 bf16
  // total ws use: ~10 MB

  // scratch inside d_out (134 MB, fully overwritten by kf at the end):
  float* outp = (float*)d_out;
  float* T   = outp + 16777216;    // 8192*336 f32   =  2,752,512
  float* zf  = outp + 21626880;    // 8192*320 f32   =  2,621,440  (ends 24,248,320 < 33,554,432)

  k0_prep<<<dim3(9), dim3(256), 0, stream>>>(seed, Wq, bq, Wk, bk, A_bfT, sb);
  kp1<<<dim3(256), dim3(352), 0, stream>>>(cq_w, cq_b, ck_w, ck_b, M, vbias);
  kp2<<<dim3(257), dim3(352), 0, stream>>>(Wo, bo, M, vbias, MM, vb2);
  kp3<<<dim3(321), dim3(256), 0, stream>>>(cv_w, cv_b, w1m, b1m, CV1, cb1);
  kcast<<<dim3(769), dim3(256), 0, stream>>>(fw1, fw2, geom_w, W1t, W2t, geomT);
  kgm<<<dim3(2048), dim3(256), 0, stream>>>(x, A_bfT, sb, Wv, bv, MM, vb2, T);
  kg3<<<dim3(2048), dim3(256), 0, stream>>>(x, pos, T, centers, widths, geomT, geom_b, zf);
  gb2<<<dim3(1024), dim3(256), 0, stream>>>(zf, CV1, cb1, w2m, b2m, updw);
  kf<<<dim3(2048), dim3(512), 0, stream>>>(x, updw, W1t, W2t, fb1, fb2, g1, be1, g2, be2, outp);
}